// Round 3
// baseline (275.598 us; speedup 1.0000x reference)
//
#include <hip/hip_runtime.h>

#define NNODES 40960
#define NEDGES 81920
#define NG     1024
#define NCOMBO 512
#define CAP    512   // bucket capacity per combo (mean 160, P(>512) ~ 0)

// ---------- fused node encoder: x, out_init = bias + x@root; also zero cnt ---
// block = 256 threads = 4 nodes x 64 dims
__global__ __launch_bounds__(256) void k_node(
    const int* __restrict__ nf, const float* __restrict__ emb,
    const float* __restrict__ root, const float* __restrict__ bias,
    float* __restrict__ x, float* __restrict__ out, int* __restrict__ cnt) {
    __shared__ float sx[4][64];
    const int t = threadIdx.x;
    if (blockIdx.x < 2) cnt[blockIdx.x * 256 + t] = 0;   // zero combo counters
    const int ln = t >> 6;                 // local node 0..3
    const int d  = t & 63;
    const int n  = blockIdx.x * 4 + ln;
    const int* nfr = nf + n * 9;
    float acc = 0.f;
#pragma unroll
    for (int c = 0; c < 9; ++c) {
        int idx = nfr[c];
        acc += emb[((c << 7) + idx) * 64 + d];
    }
    x[n * 64 + d] = acc;
    sx[ln][d] = acc;
    __syncthreads();
    if (d < 32) {
        float o = bias[d];
#pragma unroll
        for (int k = 0; k < 64; ++k) o += sx[ln][k] * root[k * 32 + d];
        out[n * 32 + d] = o;
    }
}

// ---------- fused prep: bucket-by-combo | per-graph dst-CSR | h1 MLP ----------
// blocks [0,320):    bucket edges into bkt[c*CAP + p] = (src, edge_id)
// blocks [320,1344): per-graph dst counting-sort (deterministic CSR)
// blocks [1344,1856): h1[c,:] = relu(etab[c] @ gW1), etab computed on the fly
__global__ __launch_bounds__(256) void k_prep(
    const int* __restrict__ ef, const int* __restrict__ src,
    const int* __restrict__ dst, const float* __restrict__ bemb,
    const float* __restrict__ gW1, int* __restrict__ cnt,
    int2* __restrict__ bkt, int* __restrict__ midx,
    int* __restrict__ nstart, int* __restrict__ ncnt,
    float* __restrict__ h1) {
    __shared__ int  ldst[80];
    __shared__ int  scnt[40];
    __shared__ int  base[40];
    __shared__ float se[16];
    const int b = blockIdx.x, t = threadIdx.x;

    if (b < 320) {                          // ---- bucket by combo ----
        int e = b * 256 + t;
        int c = (ef[e * 3] << 6) | (ef[e * 3 + 1] << 3) | ef[e * 3 + 2];
        int p = atomicAdd(&cnt[c], 1);
        if (p < CAP) bkt[c * CAP + p] = make_int2(src[e], e);
    } else if (b < 1344) {                  // ---- dst counting-sort ----
        const int g = b - 320;
        if (t < 40) scnt[t] = 0;
        __syncthreads();
        int d = -1;
        if (t < 80) {
            d = dst[g * 80 + t] - g * 40;   // local node 0..39
            ldst[t] = d;
            atomicAdd(&scnt[d], 1);
        }
        __syncthreads();
        if (t == 0) {
            int s = 0;
            for (int l = 0; l < 40; ++l) { base[l] = s; s += scnt[l]; }
        }
        __syncthreads();
        if (t < 80) {
            int r = 0;
            for (int j = 0; j < t; ++j) r += (ldst[j] == d);   // stable rank
            midx[g * 80 + base[d] + r] = g * 80 + t;
        }
        if (t < 40) {
            nstart[g * 40 + t] = g * 80 + base[t];
            ncnt[g * 40 + t]   = scnt[t];
        }
    } else {                                // ---- h1 = relu(etab @ gW1) ----
        const int c = b - 1344;
        if (t < 16) {
            int f0 = c >> 6, f1 = (c >> 3) & 7, f2 = c & 7;
            se[t] = bemb[f0 * 16 + t] + bemb[(8 + f1) * 16 + t] +
                    bemb[(16 + f2) * 16 + t];
        }
        __syncthreads();
        float a[16];
#pragma unroll
        for (int k = 0; k < 16; ++k) a[k] = se[k];
#pragma unroll
        for (int j = 0; j < 4; ++j) {
            int n = t + j * 256;
            float acc = 0.f;
#pragma unroll
            for (int k = 0; k < 16; ++k) acc += a[k] * gW1[k * 1024 + n];
            h1[c * 1024 + n] = fmaxf(acc, 0.f);
        }
    }
}

// ---------- single-pass GEMM, 16x64 tile, BK=32, reg-prefetch dbuf ----------
// C[M,N] = relu?(A[M,K] @ B[K,N] + bias). K % 32 == 0, N % 64 == 0, M % 16 == 0.
template <int RELU>
__global__ __launch_bounds__(256) void k_gemm1(
    const float* __restrict__ A, const float* __restrict__ B,
    const float* __restrict__ bias, float* __restrict__ C,
    int M, int N, int K) {
    constexpr int BM = 16, BN = 64, BK = 32;
    __shared__ float As[BK][BM + 2];
    __shared__ float Bs[BK][BN];
    const int t  = threadIdx.x;
    const int tx = t & 31;                  // 2 cols each
    const int ty = t >> 5;                  // 2 rows each
    const int row0 = blockIdx.y * BM, col0 = blockIdx.x * BN;

    const int am = t >> 3;                  // 0..15 (t<128)
    const int ak = (t & 7) << 2;            // 0,4,...,28
    const int bk = t >> 4;                  // 0..15
    const int bn = (t & 15) << 2;           // 0..60

    float4 av = {0,0,0,0}, bv0, bv1;
    if (t < 128) av = *reinterpret_cast<const float4*>(&A[(row0 + am) * K + ak]);
    bv0 = *reinterpret_cast<const float4*>(&B[bk * N + col0 + bn]);
    bv1 = *reinterpret_cast<const float4*>(&B[(bk + 16) * N + col0 + bn]);

    float acc[2][2] = {};
    for (int k0 = 0; k0 < K; k0 += BK) {
        if (t < 128) {
            As[ak + 0][am] = av.x; As[ak + 1][am] = av.y;
            As[ak + 2][am] = av.z; As[ak + 3][am] = av.w;
        }
        *reinterpret_cast<float4*>(&Bs[bk][bn]) = bv0;
        *reinterpret_cast<float4*>(&Bs[bk + 16][bn]) = bv1;
        __syncthreads();
        int k1 = k0 + BK;
        if (k1 < K) {                       // prefetch next tile into regs
            if (t < 128)
                av = *reinterpret_cast<const float4*>(&A[(row0 + am) * K + k1 + ak]);
            bv0 = *reinterpret_cast<const float4*>(&B[(k1 + bk) * N + col0 + bn]);
            bv1 = *reinterpret_cast<const float4*>(&B[(k1 + bk + 16) * N + col0 + bn]);
        }
#pragma unroll
        for (int k = 0; k < BK; ++k) {
            float a0 = As[k][ty * 2 + 0], a1 = As[k][ty * 2 + 1];
            float2 bb = *reinterpret_cast<const float2*>(&Bs[k][tx * 2]);
            acc[0][0] += a0 * bb.x; acc[0][1] += a0 * bb.y;
            acc[1][0] += a1 * bb.x; acc[1][1] += a1 * bb.y;
        }
        __syncthreads();
    }
#pragma unroll
    for (int i = 0; i < 2; ++i) {
        int r = row0 + ty * 2 + i;
        int c = col0 + tx * 2;
        float2 v; v.x = acc[i][0]; v.y = acc[i][1];
        if (bias) { v.x += bias[c]; v.y += bias[c + 1]; }
        if (RELU) { v.x = fmaxf(v.x, 0.f); v.y = fmaxf(v.y, 0.f); }
        *reinterpret_cast<float2*>(&C[r * N + c]) = v;
    }
}

// ---------- per-edge message, grouped by combo, no atomics ----------
// grid = NCOMBO*4; block = 256 (8 edge-slots x 32 cols). W column in 64 VGPRs.
__global__ __launch_bounds__(256) void k_msgw(
    const float* __restrict__ x, const float* __restrict__ wtab,
    const int* __restrict__ cnt, const int2* __restrict__ bkt,
    float* __restrict__ msg) {
    const int c    = blockIdx.x >> 2;
    const int sub  = blockIdx.x & 3;
    const int t    = threadIdx.x;
    const int o    = t & 31;
    const int slot = t >> 5;
    int n = cnt[c]; if (n > CAP) n = CAP;
    if (sub * 8 >= n) return;

    const float* w = wtab + c * 2048 + o;
    float wr[64];
#pragma unroll
    for (int k = 0; k < 64; ++k) wr[k] = w[k * 32];

    __shared__ float sx[8][64];
    const int2* bc = bkt + c * CAP;

    int idx  = sub * 8 + slot;
    bool act = idx < n;
    float xa = 0.f, xb = 0.f; int ecur = 0;
    if (act) {
        int2 se = bc[idx];
        ecur = se.y;
        const float* xr = x + se.x * 64;
        xa = xr[o]; xb = xr[o + 32];
    }
    while (__any(act)) {
        if (act) { sx[slot][o] = xa; sx[slot][o + 32] = xb; }
        int nidx  = idx + 32;
        bool nact = nidx < n;
        float na = 0.f, nb = 0.f; int ne = 0;
        if (nact) {
            int2 se = bc[nidx];
            ne = se.y;
            const float* xr = x + se.x * 64;
            na = xr[o]; nb = xr[o + 32];
        }
        if (act) {
            float acc = 0.f;
            const float4* xv = reinterpret_cast<const float4*>(sx[slot]);
#pragma unroll
            for (int k4 = 0; k4 < 16; ++k4) {
                float4 v = xv[k4];
                acc += v.x * wr[4 * k4 + 0];
                acc += v.y * wr[4 * k4 + 1];
                acc += v.z * wr[4 * k4 + 2];
                acc += v.w * wr[4 * k4 + 3];
            }
            msg[ecur * 32 + o] = acc;
        }
        idx = nidx; act = nact; xa = na; xb = nb; ecur = ne;
    }
}

// ---------- gather-reduce messages per node (deterministic CSR order) --------
__global__ void k_msgred(const float* __restrict__ msg, const int* __restrict__ midx,
                         const int* __restrict__ nstart, const int* __restrict__ ncnt,
                         float* __restrict__ out) {
    int gid = blockIdx.x * blockDim.x + threadIdx.x;   // NNODES*32
    int n = gid >> 5, o = gid & 31;
    int s = nstart[n], c = ncnt[n];
    float acc = out[gid];                               // root + bias
    for (int j = 0; j < c; ++j) {
        int e = midx[s + j];
        acc += msg[e * 32 + o];
    }
    out[gid] = acc;
}

// ---------- fused readout tail: f1 -> f2 -> f3 -> f4 -> out, 2 graphs/block --
__global__ __launch_bounds__(256) void k_tail2(
    const float* __restrict__ f1,
    const float* __restrict__ mW2, const float* __restrict__ mb2,
    const float* __restrict__ mW3, const float* __restrict__ mb3,
    const float* __restrict__ mW4, const float* __restrict__ mb4,
    const float* __restrict__ mW5, const float* __restrict__ mb5,
    float* __restrict__ outv) {
    __shared__ float sf1[2][256];
    __shared__ float s2[2][128];
    __shared__ float s3[2][32];
    __shared__ float s4[2][8];
    const int t  = threadIdx.x;
    const int g0 = blockIdx.x * 2;
    sf1[0][t] = f1[g0 * 256 + t];
    sf1[1][t] = f1[g0 * 256 + 256 + t];
    __syncthreads();
    {   // f2 = relu(f1 @ mW2 + mb2): 2 graphs x 128 cols
        const int wg = t >> 7, cc = t & 127;
        float acc = mb2[cc];
#pragma unroll 8
        for (int k = 0; k < 256; ++k) acc += sf1[wg][k] * mW2[k * 128 + cc];
        s2[wg][cc] = fmaxf(acc, 0.f);
    }
    __syncthreads();
    if (t < 64) {   // f3: 2 graphs x 32 cols
        const int wg = t >> 5, cc = t & 31;
        float acc = mb3[cc];
#pragma unroll 8
        for (int k = 0; k < 128; ++k) acc += s2[wg][k] * mW3[k * 32 + cc];
        s3[wg][cc] = fmaxf(acc, 0.f);
    }
    __syncthreads();
    if (t < 16) {   // f4: 2 graphs x 8 cols
        const int wg = t >> 3, cc = t & 7;
        float acc = mb4[cc];
#pragma unroll
        for (int k = 0; k < 32; ++k) acc += s3[wg][k] * mW4[k * 8 + cc];
        s4[wg][cc] = fmaxf(acc, 0.f);
    }
    __syncthreads();
    if (t < 2) {    // final scalar
        float acc = mb5[0];
#pragma unroll
        for (int k = 0; k < 8; ++k) acc += s4[t][k] * mW5[k];
        outv[g0 + t] = acc;
    }
}

extern "C" void kernel_launch(void* const* d_in, const int* in_sizes, int n_in,
                              void* d_out, int out_size, void* d_ws, size_t ws_size,
                              hipStream_t stream) {
    const int*   nf      = (const int*)d_in[0];
    const int*   ef      = (const int*)d_in[1];
    const int*   eidx    = (const int*)d_in[2];
    const float* atom_emb= (const float*)d_in[4];
    const float* bond_emb= (const float*)d_in[5];
    const float* gW1     = (const float*)d_in[6];
    const float* gW2     = (const float*)d_in[7];
    const float* gW3     = (const float*)d_in[8];
    const float* root    = (const float*)d_in[9];
    const float* cbias   = (const float*)d_in[10];
    const float* mW1     = (const float*)d_in[11];
    const float* mb1     = (const float*)d_in[12];
    const float* mW2     = (const float*)d_in[13];
    const float* mb2     = (const float*)d_in[14];
    const float* mW3     = (const float*)d_in[15];
    const float* mb3     = (const float*)d_in[16];
    const float* mW4     = (const float*)d_in[17];
    const float* mb4     = (const float*)d_in[18];
    const float* mW5     = (const float*)d_in[19];
    const float* mb5     = (const float*)d_in[20];

    const int* src = eidx;
    const int* dst = eidx + NEDGES;

    float* ws = (float*)d_ws;
    float* x    = ws;                        // 40960*64   = 2621440
    float* out  = x + 2621440;               // 40960*32   = 1310720
    float* h1   = out + 1310720;             // 512*1024   = 524288
    float* h2   = h1 + 524288;               // 512*256    = 131072
    float* wtab = h2 + 131072;               // 512*2048   = 1048576
    float* f1   = wtab + 1048576;            // 1024*256   = 262144
    float* msg  = f1 + 262144;               // 81920*32   = 2621440
    int*   cnt  = (int*)(msg + 2621440);     // 512
    int2*  bkt  = (int2*)(cnt + 512);        // 512*CAP int2
    int*   midx = (int*)(bkt + NCOMBO * CAP);// 81920
    int*   nstart = midx + 81920;            // 40960
    int*   ncnt   = nstart + 40960;          // 40960

    // 1. node encoder + root init (+ zero combo counters)
    k_node<<<NNODES / 4, 256, 0, stream>>>(nf, atom_emb, root, cbias, x, out, cnt);
    // 2. fused prep: combo-bucket | dst-CSR | h1
    k_prep<<<320 + NG + NCOMBO, 256, 0, stream>>>(ef, src, dst, bond_emb, gW1,
                                                  cnt, bkt, midx, nstart, ncnt, h1);
    // 3. h2 = relu(h1 @ gW2): 512x256, K=1024
    k_gemm1<1><<<dim3(256 / 64, 512 / 16), 256, 0, stream>>>(h1, gW2, nullptr, h2,
                                                             NCOMBO, 256, 1024);
    // 4. wtab = h2 @ gW3: 512x2048, K=256
    k_gemm1<0><<<dim3(2048 / 64, 512 / 16), 256, 0, stream>>>(h2, gW3, nullptr, wtab,
                                                              NCOMBO, 2048, 256);
    // 5. per-edge messages (no atomics)
    k_msgw<<<NCOMBO * 4, 256, 0, stream>>>(x, wtab, cnt, bkt, msg);
    // 6. gather-reduce into out
    k_msgred<<<NNODES * 32 / 256, 256, 0, stream>>>(msg, midx, nstart, ncnt, out);
    // 7. f1 = relu(dense @ mW1 + mb1): 1024x256, K=1280 (dense == out)
    k_gemm1<1><<<dim3(256 / 64, 1024 / 16), 256, 0, stream>>>(out, mW1, mb1, f1,
                                                              NG, 256, 1280);
    // 8. fused tail: f2, f3, f4, final
    k_tail2<<<NG / 2, 256, 0, stream>>>(f1, mW2, mb2, mW3, mb3, mW4, mb4,
                                        mW5, mb5, (float*)d_out);
}

// Round 4
// 257.105 us; speedup vs baseline: 1.0719x; 1.0719x over previous
//
#include <hip/hip_runtime.h>

#define NNODES 40960
#define NEDGES 81920
#define NG     1024
#define NCOMBO 512
#define CAP    512   // bucket capacity per combo (mean 160, sd ~13; 512 = +28 sd)

// ---------- atom encoder: x[n,d] = sum_c atom_emb[c, nf[n,c], d]; zero cnt ---
__global__ void k_atom(const int* __restrict__ nf, const float* __restrict__ emb,
                       float* __restrict__ x, int* __restrict__ cnt) {
    int gid = blockIdx.x * blockDim.x + threadIdx.x;   // NNODES*64
    if (blockIdx.x < 2) cnt[blockIdx.x * 256 + threadIdx.x] = 0;
    int n = gid >> 6, d = gid & 63;
    const int* nfr = nf + n * 9;
    float acc = 0.f;
#pragma unroll
    for (int c = 0; c < 9; ++c) {
        int idx = nfr[c];
        acc += emb[((c << 7) + idx) * 64 + d];
    }
    x[gid] = acc;
}

// ---------- out_init[n,o] = bias[o] + sum_d x[n,d]*root[d,o] ----------
__global__ void k_rootinit(const float* __restrict__ x, const float* __restrict__ root,
                           const float* __restrict__ bias, float* __restrict__ out) {
    int gid = blockIdx.x * blockDim.x + threadIdx.x;   // NNODES*32
    int n = gid >> 5, o = gid & 31;
    const float* xr = x + n * 64;
    float acc = bias[o];
#pragma unroll
    for (int d = 0; d < 64; ++d) acc += xr[d] * root[d * 32 + o];
    out[gid] = acc;
}

// ---------- bucket edges by combo: bkt[c*CAP+p] = (src, edge_id) ----------
__global__ void k_bucket(const int* __restrict__ ef, const int* __restrict__ src,
                         int* __restrict__ cnt, int2* __restrict__ bkt) {
    int e = blockIdx.x * 256 + threadIdx.x;            // NEDGES % 256 == 0
    int c = (ef[e * 3] << 6) | (ef[e * 3 + 1] << 3) | ef[e * 3 + 2];
    int p = atomicAdd(&cnt[c], 1);
    if (p < CAP) bkt[c * CAP + p] = make_int2(src[e], e);
}

// ---------- blocks [0,32): etab; blocks [32,1056): per-graph dst-CSR --------
__global__ __launch_bounds__(256) void k_etab_csr(
    const float* __restrict__ bemb, float* __restrict__ etab,
    const int* __restrict__ dst, int* __restrict__ midx,
    int* __restrict__ nstart, int* __restrict__ ncnt) {
    __shared__ int ldst[80];
    __shared__ int scnt[40];
    __shared__ int base[40];
    const int b = blockIdx.x, t = threadIdx.x;
    if (b < 32) {                            // ---- etab ----
        int gid = b * 256 + t;               // 512*16
        int c = gid >> 4, j = gid & 15;
        int f0 = c >> 6, f1 = (c >> 3) & 7, f2 = c & 7;
        etab[gid] = bemb[f0 * 16 + j] + bemb[(8 + f1) * 16 + j] +
                    bemb[(16 + f2) * 16 + j];
    } else {                                 // ---- dst counting-sort ----
        const int g = b - 32;
        if (t < 40) scnt[t] = 0;
        __syncthreads();
        int d = -1;
        if (t < 80) {
            d = dst[g * 80 + t] - g * 40;    // local node 0..39
            ldst[t] = d;
            atomicAdd(&scnt[d], 1);
        }
        __syncthreads();
        if (t == 0) {
            int s = 0;
            for (int l = 0; l < 40; ++l) { base[l] = s; s += scnt[l]; }
        }
        __syncthreads();
        if (t < 80) {
            int r = 0;
            for (int j = 0; j < t; ++j) r += (ldst[j] == d);   // stable rank
            midx[g * 80 + base[d] + r] = g * 80 + t;           // original edge id
        }
        if (t < 40) {
            nstart[g * 40 + t] = g * 80 + base[t];
            ncnt[g * 40 + t]   = scnt[t];
        }
    }
}

// ---------- naive GEMM (small K only): C = relu?(A@B + bias) ----------
__global__ void k_gemm_naive(const float* __restrict__ A, const float* __restrict__ B,
                             const float* __restrict__ bias, float* __restrict__ C,
                             int M, int N, int K, int relu) {
    int gid = blockIdx.x * blockDim.x + threadIdx.x;
    if (gid >= M * N) return;
    int m = gid / N, n = gid - m * N;
    const float* a = A + m * K;
    float acc = bias ? bias[n] : 0.f;
    for (int k = 0; k < K; ++k) acc += a[k] * B[k * N + n];
    if (relu) acc = fmaxf(acc, 0.f);
    C[gid] = acc;
}

// ---------- tiled GEMM, 64x64 block tile, 4x4 micro tile, split-K over z ------
template <int BM, int BN, int BK, int TM, int TN>
__global__ __launch_bounds__(256)
void k_gemm_tiled(const float* __restrict__ A, const float* __restrict__ B,
                  const float* __restrict__ bias, float* __restrict__ C,
                  float* __restrict__ Cp, int M, int N, int K, int KS, int relu) {
    constexpr int TX = BN / TN;                 // 16
    constexpr int TY = BM / TM;                 // 16
    static_assert(TX * TY == 256, "block must be 256 threads");
    __shared__ float As[BK][BM + 4];            // transposed A tile
    __shared__ float Bs[BK][BN + 4];
    const int tx = threadIdx.x % TX, ty = threadIdx.x / TX;
    const int row0 = blockIdx.y * BM, col0 = blockIdx.x * BN;
    const int z = blockIdx.z;
    const int k_begin = z * KS, k_end = k_begin + KS;

    const int am = threadIdx.x >> 2;            // 0..63
    const int ak = (threadIdx.x & 3) << 2;      // 0,4,8,12
    const int bk = threadIdx.x >> 4;            // 0..15
    const int bn = (threadIdx.x & 15) << 2;     // 0..60

    float acc[TM][TN] = {};
    for (int k0 = k_begin; k0 < k_end; k0 += BK) {
        float4 av = *reinterpret_cast<const float4*>(&A[(row0 + am) * K + k0 + ak]);
        float4 bv = *reinterpret_cast<const float4*>(&B[(k0 + bk) * N + col0 + bn]);
        As[ak + 0][am] = av.x;
        As[ak + 1][am] = av.y;
        As[ak + 2][am] = av.z;
        As[ak + 3][am] = av.w;
        *reinterpret_cast<float4*>(&Bs[bk][bn]) = bv;
        __syncthreads();
#pragma unroll
        for (int k = 0; k < BK; ++k) {
            float a[TM], b[TN];
            *reinterpret_cast<float4*>(a) =
                *reinterpret_cast<const float4*>(&As[k][ty * TM]);
            *reinterpret_cast<float4*>(b) =
                *reinterpret_cast<const float4*>(&Bs[k][tx * TN]);
#pragma unroll
            for (int i = 0; i < TM; ++i)
#pragma unroll
                for (int j = 0; j < TN; ++j) acc[i][j] += a[i] * b[j];
        }
        __syncthreads();
    }

    const int MN = M * N;
    if (gridDim.z == 1) {
#pragma unroll
        for (int i = 0; i < TM; ++i) {
            int r = row0 + ty * TM + i;
            float4 v;
            v.x = acc[i][0]; v.y = acc[i][1]; v.z = acc[i][2]; v.w = acc[i][3];
            int c = col0 + tx * TN;
            if (bias) { v.x += bias[c]; v.y += bias[c+1]; v.z += bias[c+2]; v.w += bias[c+3]; }
            if (relu) { v.x = fmaxf(v.x,0.f); v.y = fmaxf(v.y,0.f);
                        v.z = fmaxf(v.z,0.f); v.w = fmaxf(v.w,0.f); }
            *reinterpret_cast<float4*>(&C[r * N + c]) = v;
        }
    } else {
        float* dstp = Cp + z * MN;
#pragma unroll
        for (int i = 0; i < TM; ++i) {
            int r = row0 + ty * TM + i;
            float4 v;
            v.x = acc[i][0]; v.y = acc[i][1]; v.z = acc[i][2]; v.w = acc[i][3];
            *reinterpret_cast<float4*>(&dstp[r * N + col0 + tx * TN]) = v;
        }
    }
}

// ---------- split-K reduce: C = relu?(sum_z Cp[z] + bias) ----------
__global__ void k_reduceK(const float* __restrict__ Cp, const float* __restrict__ bias,
                          float* __restrict__ C, int MN, int N, int nz, int relu) {
    int i4 = (blockIdx.x * 256 + threadIdx.x) * 4;
    if (i4 >= MN) return;
    float4 acc = *reinterpret_cast<const float4*>(&Cp[i4]);
    for (int z = 1; z < nz; ++z) {
        float4 t = *reinterpret_cast<const float4*>(&Cp[z * MN + i4]);
        acc.x += t.x; acc.y += t.y; acc.z += t.z; acc.w += t.w;
    }
    if (bias) {
        int c = i4 % N;
        acc.x += bias[c]; acc.y += bias[c + 1]; acc.z += bias[c + 2]; acc.w += bias[c + 3];
    }
    if (relu) {
        acc.x = fmaxf(acc.x, 0.f); acc.y = fmaxf(acc.y, 0.f);
        acc.z = fmaxf(acc.z, 0.f); acc.w = fmaxf(acc.w, 0.f);
    }
    *reinterpret_cast<float4*>(&C[i4]) = acc;
}

// ---------- per-edge message, one block per combo, no atomics ----------
// block = 256 (8 edge-slots x 32 cols). W column in 64 VGPRs, loaded once.
__global__ __launch_bounds__(256) void k_msgw(
    const float* __restrict__ x, const float* __restrict__ wtab,
    const int* __restrict__ cnt, const int2* __restrict__ bkt,
    float* __restrict__ msg) {
    const int c    = blockIdx.x;
    const int t    = threadIdx.x;
    const int o    = t & 31;
    const int slot = t >> 5;
    int n = cnt[c]; if (n > CAP) n = CAP;
    if (n == 0) return;

    const float* w = wtab + c * 2048 + o;
    float wr[64];
#pragma unroll
    for (int k = 0; k < 64; ++k) wr[k] = w[k * 32];

    __shared__ float sx[8][64];
    const int2* bc = bkt + c * CAP;

    int idx  = slot;
    bool act = idx < n;
    float xa = 0.f, xb = 0.f; int ecur = 0;
    if (act) {
        int2 se = bc[idx];
        ecur = se.y;
        const float* xr = x + se.x * 64;
        xa = xr[o]; xb = xr[o + 32];
    }
    while (__any(act)) {
        if (act) { sx[slot][o] = xa; sx[slot][o + 32] = xb; }
        int nidx  = idx + 8;                     // next edge for this slot
        bool nact = nidx < n;
        float na = 0.f, nb = 0.f; int ne = 0;
        if (nact) {
            int2 se = bc[nidx];
            ne = se.y;
            const float* xr = x + se.x * 64;
            na = xr[o]; nb = xr[o + 32];
        }
        if (act) {
            float acc = 0.f;
            const float4* xv = reinterpret_cast<const float4*>(sx[slot]);
#pragma unroll
            for (int k4 = 0; k4 < 16; ++k4) {
                float4 v = xv[k4];
                acc += v.x * wr[4 * k4 + 0];
                acc += v.y * wr[4 * k4 + 1];
                acc += v.z * wr[4 * k4 + 2];
                acc += v.w * wr[4 * k4 + 3];
            }
            msg[ecur * 32 + o] = acc;
        }
        idx = nidx; act = nact; xa = na; xb = nb; ecur = ne;
    }
}

// ---------- gather-reduce messages per node (deterministic CSR order) --------
__global__ void k_msgred(const float* __restrict__ msg, const int* __restrict__ midx,
                         const int* __restrict__ nstart, const int* __restrict__ ncnt,
                         float* __restrict__ out) {
    int gid = blockIdx.x * blockDim.x + threadIdx.x;   // NNODES*32
    int n = gid >> 5, o = gid & 31;
    int s = nstart[n], c = ncnt[n];
    float acc = out[gid];                               // root + bias
    for (int j = 0; j < c; ++j) {
        int e = midx[s + j];
        acc += msg[e * 32 + o];
    }
    out[gid] = acc;
}

// ---------- fused readout tail: f2[1024,128] -> f3 -> f4 -> out[1024] --------
__global__ __launch_bounds__(256) void k_tail(
    const float* __restrict__ f2,
    const float* __restrict__ mW3, const float* __restrict__ mb3,
    const float* __restrict__ mW4, const float* __restrict__ mb4,
    const float* __restrict__ mW5, const float* __restrict__ mb5,
    float* __restrict__ outv) {
    __shared__ float s2[4][128];
    __shared__ float s3[4][32];
    __shared__ float s4[4][8];
    const int w = threadIdx.x >> 6, lane = threadIdx.x & 63;
    const int g = blockIdx.x * 4 + w;
    s2[w][lane] = f2[g * 128 + lane];
    s2[w][64 + lane] = f2[g * 128 + 64 + lane];
    __syncthreads();
    if (lane < 32) {
        float acc = mb3[lane];
#pragma unroll 8
        for (int k = 0; k < 128; ++k) acc += s2[w][k] * mW3[k * 32 + lane];
        s3[w][lane] = fmaxf(acc, 0.f);
    }
    __syncthreads();
    if (lane < 8) {
        float acc = mb4[lane];
#pragma unroll
        for (int k = 0; k < 32; ++k) acc += s3[w][k] * mW4[k * 8 + lane];
        s4[w][lane] = fmaxf(acc, 0.f);
    }
    __syncthreads();
    if (lane == 0) {
        float acc = mb5[0];
#pragma unroll
        for (int k = 0; k < 8; ++k) acc += s4[w][k] * mW5[k];
        outv[g] = acc;
    }
}

extern "C" void kernel_launch(void* const* d_in, const int* in_sizes, int n_in,
                              void* d_out, int out_size, void* d_ws, size_t ws_size,
                              hipStream_t stream) {
    const int*   nf      = (const int*)d_in[0];
    const int*   ef      = (const int*)d_in[1];
    const int*   eidx    = (const int*)d_in[2];
    const float* atom_emb= (const float*)d_in[4];
    const float* bond_emb= (const float*)d_in[5];
    const float* gW1     = (const float*)d_in[6];
    const float* gW2     = (const float*)d_in[7];
    const float* gW3     = (const float*)d_in[8];
    const float* root    = (const float*)d_in[9];
    const float* cbias   = (const float*)d_in[10];
    const float* mW1     = (const float*)d_in[11];
    const float* mb1     = (const float*)d_in[12];
    const float* mW2     = (const float*)d_in[13];
    const float* mb2     = (const float*)d_in[14];
    const float* mW3     = (const float*)d_in[15];
    const float* mb3     = (const float*)d_in[16];
    const float* mW4     = (const float*)d_in[17];
    const float* mb4     = (const float*)d_in[18];
    const float* mW5     = (const float*)d_in[19];
    const float* mb5     = (const float*)d_in[20];

    const int* src = eidx;
    const int* dst = eidx + NEDGES;

    float* ws = (float*)d_ws;
    float* x    = ws;                        // 40960*64   = 2621440
    float* out  = x + 2621440;               // 40960*32   = 1310720
    float* etab = out + 1310720;             // 512*16     = 8192
    float* h1   = etab + 8192;               // 512*1024   = 524288
    float* h2   = h1 + 524288;               // 512*256    = 131072
    float* wtab = h2 + 131072;               // 512*2048   = 1048576
    float* f1   = wtab + 1048576;            // 1024*256   = 262144
    float* f2   = f1 + 262144;               // 1024*128   = 131072
    float* part = f2 + 131072;               // 2097152 (8 MB split-K partials)
    float* msg  = part + 2097152;            // 81920*32   = 2621440
    int*   cnt  = (int*)(msg + 2621440);     // 512
    int2*  bkt  = (int2*)(cnt + 512);        // 512*CAP int2
    int*   midx = (int*)(bkt + NCOMBO * CAP);// 81920
    int*   nstart = midx + 81920;            // 40960
    int*   ncnt   = nstart + 40960;          // 40960

    // 1. atom encoder (+ zero combo counters) + root transform
    k_atom<<<NNODES * 64 / 256, 256, 0, stream>>>(nf, atom_emb, x, cnt);
    k_rootinit<<<NNODES * 32 / 256, 256, 0, stream>>>(x, root, cbias, out);
    // 2. combo bucketing + (etab | per-graph dst-CSR)
    k_bucket<<<NEDGES / 256, 256, 0, stream>>>(ef, src, cnt, bkt);
    k_etab_csr<<<32 + NG, 256, 0, stream>>>(bond_emb, etab, dst, midx, nstart, ncnt);
    // 3. edge MLP on 512 unique combos (round-0 verified GEMM structure)
    k_gemm_naive<<<NCOMBO * 1024 / 256, 256, 0, stream>>>(etab, gW1, nullptr, h1,
                                                          NCOMBO, 1024, 16, 1);
    k_gemm_tiled<64, 64, 16, 4, 4><<<dim3(4, 8, 16), 256, 0, stream>>>(
        h1, gW2, nullptr, nullptr, part, NCOMBO, 256, 1024, 64, 0);
    k_reduceK<<<131072 / 1024, 256, 0, stream>>>(part, nullptr, h2, 131072, 256, 16, 1);
    k_gemm_tiled<64, 64, 16, 4, 4><<<dim3(32, 8, 2), 256, 0, stream>>>(
        h2, gW3, nullptr, nullptr, part, NCOMBO, 2048, 256, 128, 0);
    k_reduceK<<<1048576 / 1024, 256, 0, stream>>>(part, nullptr, wtab, 1048576, 2048, 2, 0);
    // 4. per-edge messages (combo-grouped, no atomics) + CSR gather-reduce
    k_msgw<<<NCOMBO, 256, 0, stream>>>(x, wtab, cnt, bkt, msg);
    k_msgred<<<NNODES * 32 / 256, 256, 0, stream>>>(msg, midx, nstart, ncnt, out);
    // 5. readout: f1 = relu(dense @ mW1 + mb1), dense == out viewed [1024,1280]
    k_gemm_tiled<64, 64, 16, 4, 4><<<dim3(4, 16, 8), 256, 0, stream>>>(
        out, mW1, nullptr, nullptr, part, NG, 256, 1280, 160, 0);
    k_reduceK<<<262144 / 1024, 256, 0, stream>>>(part, mb1, f1, 262144, 256, 8, 1);
    // f2 = relu(f1 @ mW2 + mb2): 1024x128, K=256, split 4x64
    k_gemm_tiled<64, 64, 16, 4, 4><<<dim3(2, 16, 4), 256, 0, stream>>>(
        f1, mW2, nullptr, nullptr, part, NG, 128, 256, 64, 0);
    k_reduceK<<<131072 / 1024, 256, 0, stream>>>(part, mb2, f2, 131072, 128, 4, 1);
    // 6. fused tail: f3, f4, final
    k_tail<<<NG / 4, 256, 0, stream>>>(f2, mW3, mb3, mW4, mb4, mW5, mb5, (float*)d_out);
}

// Round 5
// 255.908 us; speedup vs baseline: 1.0769x; 1.0047x over previous
//
#include <hip/hip_runtime.h>

#define NNODES 40960
#define NEDGES 81920
#define NG     1024
#define NCOMBO 512
#define CAP    256   // bucket capacity per combo (mean 160, sd ~12.6; 256 = +7.6 sd)

// ---------- atom encoder: x[n,d] = sum_c atom_emb[c, nf[n,c], d]; zero cnt ---
__global__ void k_atom(const int* __restrict__ nf, const float* __restrict__ emb,
                       float* __restrict__ x, int* __restrict__ cnt) {
    int gid = blockIdx.x * blockDim.x + threadIdx.x;   // NNODES*64
    if (blockIdx.x < 2) cnt[blockIdx.x * 256 + threadIdx.x] = 0;
    int n = gid >> 6, d = gid & 63;
    const int* nfr = nf + n * 9;
    float acc = 0.f;
#pragma unroll
    for (int c = 0; c < 9; ++c) {
        int idx = nfr[c];
        acc += emb[((c << 7) + idx) * 64 + d];
    }
    x[gid] = acc;
}

// ---------- out_init[n,o] = bias[o] + sum_d x[n,d]*root[d,o] ----------
__global__ void k_rootinit(const float* __restrict__ x, const float* __restrict__ root,
                           const float* __restrict__ bias, float* __restrict__ out) {
    int gid = blockIdx.x * blockDim.x + threadIdx.x;   // NNODES*32
    int n = gid >> 5, o = gid & 31;
    const float* xr = x + n * 64;
    float acc = bias[o];
#pragma unroll
    for (int d = 0; d < 64; ++d) acc += xr[d] * root[d * 32 + o];
    out[gid] = acc;
}

// ---------- bucket edges by combo: bkt[c*CAP+p] = (src, dst) ----------
__global__ void k_bucket(const int* __restrict__ ef, const int* __restrict__ src,
                         const int* __restrict__ dst, int* __restrict__ cnt,
                         int2* __restrict__ bkt) {
    int e = blockIdx.x * 256 + threadIdx.x;            // NEDGES % 256 == 0
    int c = (ef[e * 3] << 6) | (ef[e * 3 + 1] << 3) | ef[e * 3 + 2];
    int p = atomicAdd(&cnt[c], 1);
    if (p < CAP) bkt[c * CAP + p] = make_int2(src[e], dst[e]);
}

// ---------- etab[c,j] = sum of 3 bond embeddings ----------
__global__ void k_etab(const float* __restrict__ bemb, float* __restrict__ etab) {
    int gid = blockIdx.x * blockDim.x + threadIdx.x;   // 512*16
    int c = gid >> 4, j = gid & 15;
    int f0 = c >> 6, f1 = (c >> 3) & 7, f2 = c & 7;
    etab[gid] = bemb[(0 * 8 + f0) * 16 + j] + bemb[(1 * 8 + f1) * 16 + j] +
                bemb[(2 * 8 + f2) * 16 + j];
}

// ---------- naive GEMM (small K only): C = relu?(A@B + bias) ----------
__global__ void k_gemm_naive(const float* __restrict__ A, const float* __restrict__ B,
                             const float* __restrict__ bias, float* __restrict__ C,
                             int M, int N, int K, int relu) {
    int gid = blockIdx.x * blockDim.x + threadIdx.x;
    if (gid >= M * N) return;
    int m = gid / N, n = gid - m * N;
    const float* a = A + m * K;
    float acc = bias ? bias[n] : 0.f;
    for (int k = 0; k < K; ++k) acc += a[k] * B[k * N + n];
    if (relu) acc = fmaxf(acc, 0.f);
    C[gid] = acc;
}

// ---------- tiled GEMM, 64x64 block tile, 4x4 micro tile, split-K over z ------
template <int BM, int BN, int BK, int TM, int TN>
__global__ __launch_bounds__(256)
void k_gemm_tiled(const float* __restrict__ A, const float* __restrict__ B,
                  const float* __restrict__ bias, float* __restrict__ C,
                  float* __restrict__ Cp, int M, int N, int K, int KS, int relu) {
    constexpr int TX = BN / TN;                 // 16
    constexpr int TY = BM / TM;                 // 16
    static_assert(TX * TY == 256, "block must be 256 threads");
    __shared__ float As[BK][BM + 4];            // transposed A tile
    __shared__ float Bs[BK][BN + 4];
    const int tx = threadIdx.x % TX, ty = threadIdx.x / TX;
    const int row0 = blockIdx.y * BM, col0 = blockIdx.x * BN;
    const int z = blockIdx.z;
    const int k_begin = z * KS, k_end = k_begin + KS;

    const int am = threadIdx.x >> 2;            // 0..63
    const int ak = (threadIdx.x & 3) << 2;      // 0,4,8,12
    const int bk = threadIdx.x >> 4;            // 0..15
    const int bn = (threadIdx.x & 15) << 2;     // 0..60

    float acc[TM][TN] = {};
    for (int k0 = k_begin; k0 < k_end; k0 += BK) {
        float4 av = *reinterpret_cast<const float4*>(&A[(row0 + am) * K + k0 + ak]);
        float4 bv = *reinterpret_cast<const float4*>(&B[(k0 + bk) * N + col0 + bn]);
        As[ak + 0][am] = av.x;
        As[ak + 1][am] = av.y;
        As[ak + 2][am] = av.z;
        As[ak + 3][am] = av.w;
        *reinterpret_cast<float4*>(&Bs[bk][bn]) = bv;
        __syncthreads();
#pragma unroll
        for (int k = 0; k < BK; ++k) {
            float a[TM], b[TN];
            *reinterpret_cast<float4*>(a) =
                *reinterpret_cast<const float4*>(&As[k][ty * TM]);
            *reinterpret_cast<float4*>(b) =
                *reinterpret_cast<const float4*>(&Bs[k][tx * TN]);
#pragma unroll
            for (int i = 0; i < TM; ++i)
#pragma unroll
                for (int j = 0; j < TN; ++j) acc[i][j] += a[i] * b[j];
        }
        __syncthreads();
    }

    const int MN = M * N;
    if (gridDim.z == 1) {
#pragma unroll
        for (int i = 0; i < TM; ++i) {
            int r = row0 + ty * TM + i;
            float4 v;
            v.x = acc[i][0]; v.y = acc[i][1]; v.z = acc[i][2]; v.w = acc[i][3];
            int c = col0 + tx * TN;
            if (bias) { v.x += bias[c]; v.y += bias[c+1]; v.z += bias[c+2]; v.w += bias[c+3]; }
            if (relu) { v.x = fmaxf(v.x,0.f); v.y = fmaxf(v.y,0.f);
                        v.z = fmaxf(v.z,0.f); v.w = fmaxf(v.w,0.f); }
            *reinterpret_cast<float4*>(&C[r * N + c]) = v;
        }
    } else {
        float* dstp = Cp + z * MN;
#pragma unroll
        for (int i = 0; i < TM; ++i) {
            int r = row0 + ty * TM + i;
            float4 v;
            v.x = acc[i][0]; v.y = acc[i][1]; v.z = acc[i][2]; v.w = acc[i][3];
            *reinterpret_cast<float4*>(&dstp[r * N + col0 + tx * TN]) = v;
        }
    }
}

// ---------- split-K reduce: C = relu?(sum_z Cp[z] + bias) ----------
__global__ void k_reduceK(const float* __restrict__ Cp, const float* __restrict__ bias,
                          float* __restrict__ C, int MN, int N, int nz, int relu) {
    int i4 = (blockIdx.x * 256 + threadIdx.x) * 4;
    if (i4 >= MN) return;
    float4 acc = *reinterpret_cast<const float4*>(&Cp[i4]);
    for (int z = 1; z < nz; ++z) {
        float4 t = *reinterpret_cast<const float4*>(&Cp[z * MN + i4]);
        acc.x += t.x; acc.y += t.y; acc.z += t.z; acc.w += t.w;
    }
    if (bias) {
        int c = i4 % N;
        acc.x += bias[c]; acc.y += bias[c + 1]; acc.z += bias[c + 2]; acc.w += bias[c + 3];
    }
    if (relu) {
        acc.x = fmaxf(acc.x, 0.f); acc.y = fmaxf(acc.y, 0.f);
        acc.z = fmaxf(acc.z, 0.f); acc.w = fmaxf(acc.w, 0.f);
    }
    *reinterpret_cast<float4*>(&C[i4]) = acc;
}

// ---------- NNConv message + scatter, cid-sorted streaming ----------
// grid = NCOMBO * (CAP/8); block = 256 = 8 same-combo edges x 32 cols.
// Whole block shares ONE 8 KB W, staged in LDS (coalesced load, conflict-free
// reads, broadcast across the 2 edge-slots of each wave). x rows read as
// broadcast float4. Atomic scatter identical to the round-0 k_msg.
__global__ __launch_bounds__(256) void k_msgs(
    const float* __restrict__ x, const float* __restrict__ wtab,
    const int* __restrict__ cnt, const int2* __restrict__ bkt,
    float* __restrict__ out) {
    const int c   = blockIdx.x >> 5;           // combo id (CAP/8 = 32 groups)
    const int grp = blockIdx.x & 31;
    int n = cnt[c]; if (n > CAP) n = CAP;
    if (grp * 8 >= n) return;                  // block-uniform early exit

    const int t = threadIdx.x;
    const int o = t & 31, slot = t >> 5;
    __shared__ float sw[2048];
#pragma unroll
    for (int i = 0; i < 8; ++i) sw[t + i * 256] = wtab[c * 2048 + t + i * 256];
    __syncthreads();

    int p = grp * 8 + slot;
    if (p < n) {
        int2 sd = bkt[c * CAP + p];
        const float4* xv = reinterpret_cast<const float4*>(x + sd.x * 64);
        float acc = 0.f;
#pragma unroll
        for (int k4 = 0; k4 < 16; ++k4) {
            float4 v = xv[k4];
            acc += v.x * sw[(k4 * 4 + 0) * 32 + o];
            acc += v.y * sw[(k4 * 4 + 1) * 32 + o];
            acc += v.z * sw[(k4 * 4 + 2) * 32 + o];
            acc += v.w * sw[(k4 * 4 + 3) * 32 + o];
        }
        atomicAdd(&out[sd.y * 32 + o], acc);
    }
}

// ---------- fused readout tail: f2[1024,128] -> f3 -> f4 -> out[1024] --------
__global__ __launch_bounds__(256) void k_tail(
    const float* __restrict__ f2,
    const float* __restrict__ mW3, const float* __restrict__ mb3,
    const float* __restrict__ mW4, const float* __restrict__ mb4,
    const float* __restrict__ mW5, const float* __restrict__ mb5,
    float* __restrict__ outv) {
    __shared__ float s2[4][128];
    __shared__ float s3[4][32];
    __shared__ float s4[4][8];
    const int w = threadIdx.x >> 6, lane = threadIdx.x & 63;
    const int g = blockIdx.x * 4 + w;
    s2[w][lane] = f2[g * 128 + lane];
    s2[w][64 + lane] = f2[g * 128 + 64 + lane];
    __syncthreads();
    if (lane < 32) {
        float acc = mb3[lane];
#pragma unroll 8
        for (int k = 0; k < 128; ++k) acc += s2[w][k] * mW3[k * 32 + lane];
        s3[w][lane] = fmaxf(acc, 0.f);
    }
    __syncthreads();
    if (lane < 8) {
        float acc = mb4[lane];
#pragma unroll
        for (int k = 0; k < 32; ++k) acc += s3[w][k] * mW4[k * 8 + lane];
        s4[w][lane] = fmaxf(acc, 0.f);
    }
    __syncthreads();
    if (lane == 0) {
        float acc = mb5[0];
#pragma unroll
        for (int k = 0; k < 8; ++k) acc += s4[w][k] * mW5[k];
        outv[g] = acc;
    }
}

extern "C" void kernel_launch(void* const* d_in, const int* in_sizes, int n_in,
                              void* d_out, int out_size, void* d_ws, size_t ws_size,
                              hipStream_t stream) {
    const int*   nf      = (const int*)d_in[0];
    const int*   ef      = (const int*)d_in[1];
    const int*   eidx    = (const int*)d_in[2];
    const float* atom_emb= (const float*)d_in[4];
    const float* bond_emb= (const float*)d_in[5];
    const float* gW1     = (const float*)d_in[6];
    const float* gW2     = (const float*)d_in[7];
    const float* gW3     = (const float*)d_in[8];
    const float* root    = (const float*)d_in[9];
    const float* cbias   = (const float*)d_in[10];
    const float* mW1     = (const float*)d_in[11];
    const float* mb1     = (const float*)d_in[12];
    const float* mW2     = (const float*)d_in[13];
    const float* mb2     = (const float*)d_in[14];
    const float* mW3     = (const float*)d_in[15];
    const float* mb3     = (const float*)d_in[16];
    const float* mW4     = (const float*)d_in[17];
    const float* mb4     = (const float*)d_in[18];
    const float* mW5     = (const float*)d_in[19];
    const float* mb5     = (const float*)d_in[20];

    const int* src = eidx;
    const int* dst = eidx + NEDGES;

    float* ws = (float*)d_ws;
    float* x    = ws;                        // 40960*64   = 2621440
    float* out  = x + 2621440;               // 40960*32   = 1310720
    float* etab = out + 1310720;             // 512*16     = 8192
    float* h1   = etab + 8192;               // 512*1024   = 524288
    float* h2   = h1 + 524288;               // 512*256    = 131072
    float* wtab = h2 + 131072;               // 512*2048   = 1048576
    float* f1   = wtab + 1048576;            // 1024*256   = 262144
    float* f2   = f1 + 262144;               // 1024*128   = 131072
    float* part = f2 + 131072;               // 2097152 (8 MB split-K partials)
    int*   cnt  = (int*)(part + 2097152);    // 512
    int2*  bkt  = (int2*)(cnt + 512);        // 512*CAP int2 = 1 MB

    // 1. atom encoder (+ zero combo counters) + root transform
    k_atom<<<NNODES * 64 / 256, 256, 0, stream>>>(nf, atom_emb, x, cnt);
    k_rootinit<<<NNODES * 32 / 256, 256, 0, stream>>>(x, root, cbias, out);
    // 2. combo bucketing (cid-sort) + dedup'd edge embeddings
    k_bucket<<<NEDGES / 256, 256, 0, stream>>>(ef, src, dst, cnt, bkt);
    k_etab<<<NCOMBO * 16 / 256, 256, 0, stream>>>(bond_emb, etab);
    // 3. edge MLP on 512 unique combos (round-0 verified GEMM structure)
    k_gemm_naive<<<NCOMBO * 1024 / 256, 256, 0, stream>>>(etab, gW1, nullptr, h1,
                                                          NCOMBO, 1024, 16, 1);
    k_gemm_tiled<64, 64, 16, 4, 4><<<dim3(4, 8, 16), 256, 0, stream>>>(
        h1, gW2, nullptr, nullptr, part, NCOMBO, 256, 1024, 64, 0);
    k_reduceK<<<131072 / 1024, 256, 0, stream>>>(part, nullptr, h2, 131072, 256, 16, 1);
    k_gemm_tiled<64, 64, 16, 4, 4><<<dim3(32, 8, 2), 256, 0, stream>>>(
        h2, gW3, nullptr, nullptr, part, NCOMBO, 2048, 256, 128, 0);
    k_reduceK<<<1048576 / 1024, 256, 0, stream>>>(part, nullptr, wtab, 1048576, 2048, 2, 0);
    // 4. per-edge message + scatter-add, cid-sorted streaming with LDS-staged W
    k_msgs<<<NCOMBO * (CAP / 8), 256, 0, stream>>>(x, wtab, cnt, bkt, out);
    // 5. readout: f1 = relu(dense @ mW1 + mb1), dense == out viewed [1024,1280]
    k_gemm_tiled<64, 64, 16, 4, 4><<<dim3(4, 16, 8), 256, 0, stream>>>(
        out, mW1, nullptr, nullptr, part, NG, 256, 1280, 160, 0);
    k_reduceK<<<262144 / 1024, 256, 0, stream>>>(part, mb1, f1, 262144, 256, 8, 1);
    // f2 = relu(f1 @ mW2 + mb2): 1024x128, K=256, split 4x64
    k_gemm_tiled<64, 64, 16, 4, 4><<<dim3(2, 16, 4), 256, 0, stream>>>(
        f1, mW2, nullptr, nullptr, part, NG, 128, 256, 64, 0);
    k_reduceK<<<131072 / 1024, 256, 0, stream>>>(part, mb2, f2, 131072, 128, 4, 1);
    // 6. fused tail: f3, f4, final
    k_tail<<<NG / 4, 256, 0, stream>>>(f2, mW3, mb3, mW4, mb4, mW5, mb5, (float*)d_out);
}

// Round 7
// 255.810 us; speedup vs baseline: 1.0774x; 1.0004x over previous
//
#include <hip/hip_runtime.h>

#define NNODES 40960
#define NEDGES 81920
#define NG     1024
#define NCOMBO 512

// ---------- atom encoder: x[n,d] = sum_c atom_emb[c, nf[n,c], d] ----------
__global__ void k_atom(const int* __restrict__ nf, const float* __restrict__ emb,
                       float* __restrict__ x) {
    int gid = blockIdx.x * blockDim.x + threadIdx.x;   // NNODES*64
    int n = gid >> 6, d = gid & 63;
    const int* nfr = nf + n * 9;
    float acc = 0.f;
#pragma unroll
    for (int c = 0; c < 9; ++c) {
        int idx = nfr[c];
        acc += emb[((c << 7) + idx) * 64 + d];
    }
    x[gid] = acc;
}

// ---------- out_init[n,o] = bias[o] + sum_d x[n,d]*root[d,o] ----------
__global__ void k_rootinit(const float* __restrict__ x, const float* __restrict__ root,
                           const float* __restrict__ bias, float* __restrict__ out) {
    int gid = blockIdx.x * blockDim.x + threadIdx.x;   // NNODES*32
    int n = gid >> 5, o = gid & 31;
    const float* xr = x + n * 64;
    float acc = bias[o];
#pragma unroll
    for (int d = 0; d < 64; ++d) acc += xr[d] * root[d * 32 + o];
    out[gid] = acc;
}

// ---------- dedup: combo id per edge (no atomics) ----------
__global__ void k_cid(const int* __restrict__ ef, int* __restrict__ cid) {
    int e = blockIdx.x * blockDim.x + threadIdx.x;
    if (e < NEDGES)
        cid[e] = (ef[e * 3] << 6) | (ef[e * 3 + 1] << 3) | ef[e * 3 + 2];
}

// ---------- etab[c,j] = sum of 3 bond embeddings ----------
__global__ void k_etab(const float* __restrict__ bemb, float* __restrict__ etab) {
    int gid = blockIdx.x * blockDim.x + threadIdx.x;   // 512*16
    int c = gid >> 4, j = gid & 15;
    int f0 = c >> 6, f1 = (c >> 3) & 7, f2 = c & 7;
    etab[gid] = bemb[(0 * 8 + f0) * 16 + j] + bemb[(1 * 8 + f1) * 16 + j] +
                bemb[(2 * 8 + f2) * 16 + j];
}

// ---------- naive GEMM (small K only): C = relu?(A@B + bias) ----------
__global__ void k_gemm_naive(const float* __restrict__ A, const float* __restrict__ B,
                             const float* __restrict__ bias, float* __restrict__ C,
                             int M, int N, int K, int relu) {
    int gid = blockIdx.x * blockDim.x + threadIdx.x;
    if (gid >= M * N) return;
    int m = gid / N, n = gid - m * N;
    const float* a = A + m * K;
    float acc = bias ? bias[n] : 0.f;
    for (int k = 0; k < K; ++k) acc += a[k] * B[k * N + n];
    if (relu) acc = fmaxf(acc, 0.f);
    C[gid] = acc;
}

// ---------- tiled GEMM, 64x64 block tile, 4x4 micro tile, split-K over z ------
template <int BM, int BN, int BK, int TM, int TN>
__global__ __launch_bounds__(256)
void k_gemm_tiled(const float* __restrict__ A, const float* __restrict__ B,
                  const float* __restrict__ bias, float* __restrict__ C,
                  float* __restrict__ Cp, int M, int N, int K, int KS, int relu) {
    constexpr int TX = BN / TN;                 // 16
    constexpr int TY = BM / TM;                 // 16
    static_assert(TX * TY == 256, "block must be 256 threads");
    __shared__ float As[BK][BM + 4];            // transposed A tile
    __shared__ float Bs[BK][BN + 4];
    const int tx = threadIdx.x % TX, ty = threadIdx.x / TX;
    const int row0 = blockIdx.y * BM, col0 = blockIdx.x * BN;
    const int z = blockIdx.z;
    const int k_begin = z * KS, k_end = k_begin + KS;

    const int am = threadIdx.x >> 2;            // 0..63
    const int ak = (threadIdx.x & 3) << 2;      // 0,4,8,12
    const int bk = threadIdx.x >> 4;            // 0..15
    const int bn = (threadIdx.x & 15) << 2;     // 0..60

    float acc[TM][TN] = {};
    for (int k0 = k_begin; k0 < k_end; k0 += BK) {
        float4 av = *reinterpret_cast<const float4*>(&A[(row0 + am) * K + k0 + ak]);
        float4 bv = *reinterpret_cast<const float4*>(&B[(k0 + bk) * N + col0 + bn]);
        As[ak + 0][am] = av.x;
        As[ak + 1][am] = av.y;
        As[ak + 2][am] = av.z;
        As[ak + 3][am] = av.w;
        *reinterpret_cast<float4*>(&Bs[bk][bn]) = bv;
        __syncthreads();
#pragma unroll
        for (int k = 0; k < BK; ++k) {
            float a[TM], b[TN];
            *reinterpret_cast<float4*>(a) =
                *reinterpret_cast<const float4*>(&As[k][ty * TM]);
            *reinterpret_cast<float4*>(b) =
                *reinterpret_cast<const float4*>(&Bs[k][tx * TN]);
#pragma unroll
            for (int i = 0; i < TM; ++i)
#pragma unroll
                for (int j = 0; j < TN; ++j) acc[i][j] += a[i] * b[j];
        }
        __syncthreads();
    }

    const int MN = M * N;
    if (gridDim.z == 1) {
#pragma unroll
        for (int i = 0; i < TM; ++i) {
            int r = row0 + ty * TM + i;
            float4 v;
            v.x = acc[i][0]; v.y = acc[i][1]; v.z = acc[i][2]; v.w = acc[i][3];
            int c = col0 + tx * TN;
            if (bias) { v.x += bias[c]; v.y += bias[c+1]; v.z += bias[c+2]; v.w += bias[c+3]; }
            if (relu) { v.x = fmaxf(v.x,0.f); v.y = fmaxf(v.y,0.f);
                        v.z = fmaxf(v.z,0.f); v.w = fmaxf(v.w,0.f); }
            *reinterpret_cast<float4*>(&C[r * N + c]) = v;
        }
    } else {
        float* dstp = Cp + z * MN;
#pragma unroll
        for (int i = 0; i < TM; ++i) {
            int r = row0 + ty * TM + i;
            float4 v;
            v.x = acc[i][0]; v.y = acc[i][1]; v.z = acc[i][2]; v.w = acc[i][3];
            *reinterpret_cast<float4*>(&dstp[r * N + col0 + tx * TN]) = v;
        }
    }
}

// ---------- split-K reduce: C = relu?(sum_z Cp[z] + bias) ----------
__global__ void k_reduceK(const float* __restrict__ Cp, const float* __restrict__ bias,
                          float* __restrict__ C, int MN, int N, int nz, int relu) {
    int i4 = (blockIdx.x * 256 + threadIdx.x) * 4;
    if (i4 >= MN) return;
    float4 acc = *reinterpret_cast<const float4*>(&Cp[i4]);
    for (int z = 1; z < nz; ++z) {
        float4 t = *reinterpret_cast<const float4*>(&Cp[z * MN + i4]);
        acc.x += t.x; acc.y += t.y; acc.z += t.z; acc.w += t.w;
    }
    if (bias) {
        int c = i4 % N;
        acc.x += bias[c]; acc.y += bias[c + 1]; acc.z += bias[c + 2]; acc.w += bias[c + 3];
    }
    if (relu) {
        acc.x = fmaxf(acc.x, 0.f); acc.y = fmaxf(acc.y, 0.f);
        acc.z = fmaxf(acc.z, 0.f); acc.w = fmaxf(acc.w, 0.f);
    }
    *reinterpret_cast<float4*>(&C[i4]) = acc;
}

// ---------- NNConv message: identical reads to round-0 k_msg, plain store ----
__global__ void k_msgp(const float* __restrict__ x, const float* __restrict__ wtab,
                       const int* __restrict__ cid, const int* __restrict__ src,
                       float* __restrict__ msg) {
    int gid = blockIdx.x * blockDim.x + threadIdx.x;   // NEDGES*32
    int e = gid >> 5, o = gid & 31;
    int s = src[e], c = cid[e];
    const float* xr = x + s * 64;
    const float* w = wtab + c * 2048 + o;
    float acc = 0.f;
#pragma unroll
    for (int k = 0; k < 64; ++k) acc += xr[k] * w[k * 32];
    msg[gid] = acc;                                     // coalesced, no atomic
}

// ---------- per-graph gather-reduce: out[n,:] += sum_{dst[e]==n} msg[e,:] ----
// One block per graph; graph g owns edges [80g,80g+80) and nodes [40g,40g+40).
// Deterministic (ascending edge order). Zero atomics.
__global__ __launch_bounds__(256) void k_gred(
    const float* __restrict__ msg, const int* __restrict__ dst,
    float* __restrict__ out) {
    __shared__ float smsg[80][32];
    __shared__ int   sdst[80];
    const int g = blockIdx.x, t = threadIdx.x;
    // stage 80 message rows (2560 floats) coalesced
#pragma unroll
    for (int i = 0; i < 10; ++i) {
        int idx = t + i * 256;
        smsg[idx >> 5][idx & 31] = msg[g * 2560 + idx];
    }
    if (t < 80) sdst[t] = dst[g * 80 + t] - g * 40;     // local node 0..39
    __syncthreads();
    // 1280 outputs (40 nodes x 32 cols), 5 per thread
#pragma unroll
    for (int i = 0; i < 5; ++i) {
        int idx = t + i * 256;
        int n = idx >> 5, o = idx & 31;
        float acc = out[g * 1280 + idx];                // root + bias
        for (int j = 0; j < 80; ++j)
            if (sdst[j] == n) acc += smsg[j][o];
        out[g * 1280 + idx] = acc;
    }
}

// ---------- fused readout tail: f2[1024,128] -> f3 -> f4 -> out[1024] --------
__global__ __launch_bounds__(256) void k_tail(
    const float* __restrict__ f2,
    const float* __restrict__ mW3, const float* __restrict__ mb3,
    const float* __restrict__ mW4, const float* __restrict__ mb4,
    const float* __restrict__ mW5, const float* __restrict__ mb5,
    float* __restrict__ outv) {
    __shared__ float s2[4][128];
    __shared__ float s3[4][32];
    __shared__ float s4[4][8];
    const int w = threadIdx.x >> 6, lane = threadIdx.x & 63;
    const int g = blockIdx.x * 4 + w;
    s2[w][lane] = f2[g * 128 + lane];
    s2[w][64 + lane] = f2[g * 128 + 64 + lane];
    __syncthreads();
    if (lane < 32) {
        float acc = mb3[lane];
#pragma unroll 8
        for (int k = 0; k < 128; ++k) acc += s2[w][k] * mW3[k * 32 + lane];
        s3[w][lane] = fmaxf(acc, 0.f);
    }
    __syncthreads();
    if (lane < 8) {
        float acc = mb4[lane];
#pragma unroll
        for (int k = 0; k < 32; ++k) acc += s3[w][k] * mW4[k * 8 + lane];
        s4[w][lane] = fmaxf(acc, 0.f);
    }
    __syncthreads();
    if (lane == 0) {
        float acc = mb5[0];
#pragma unroll
        for (int k = 0; k < 8; ++k) acc += s4[w][k] * mW5[k];
        outv[g] = acc;
    }
}

extern "C" void kernel_launch(void* const* d_in, const int* in_sizes, int n_in,
                              void* d_out, int out_size, void* d_ws, size_t ws_size,
                              hipStream_t stream) {
    const int*   nf      = (const int*)d_in[0];
    const int*   ef      = (const int*)d_in[1];
    const int*   eidx    = (const int*)d_in[2];
    const float* atom_emb= (const float*)d_in[4];
    const float* bond_emb= (const float*)d_in[5];
    const float* gW1     = (const float*)d_in[6];
    const float* gW2     = (const float*)d_in[7];
    const float* gW3     = (const float*)d_in[8];
    const float* root    = (const float*)d_in[9];
    const float* cbias   = (const float*)d_in[10];
    const float* mW1     = (const float*)d_in[11];
    const float* mb1     = (const float*)d_in[12];
    const float* mW2     = (const float*)d_in[13];
    const float* mb2     = (const float*)d_in[14];
    const float* mW3     = (const float*)d_in[15];
    const float* mb3     = (const float*)d_in[16];
    const float* mW4     = (const float*)d_in[17];
    const float* mb4     = (const float*)d_in[18];
    const float* mW5     = (const float*)d_in[19];
    const float* mb5     = (const float*)d_in[20];

    const int* src = eidx;
    const int* dst = eidx + NEDGES;

    float* ws = (float*)d_ws;
    float* x    = ws;                       // 40960*64   = 2621440
    float* out  = x + 2621440;              // 40960*32   = 1310720
    float* etab = out + 1310720;            // 512*16     = 8192
    float* h1   = etab + 8192;              // 512*1024   = 524288
    float* h2   = h1 + 524288;              // 512*256    = 131072
    float* wtab = h2 + 131072;              // 512*2048   = 1048576
    float* f1   = wtab + 1048576;           // 1024*256   = 262144
    float* f2   = f1 + 262144;              // 1024*128   = 131072
    float* part = f2 + 131072;              // 2097152 (8 MB split-K partials)
    float* msg  = part + 2097152;           // 81920*32   = 2621440
    int*   cid  = (int*)(msg + 2621440);    // 81920 ints

    // 1. atom encoder + root transform (agg initializer)
    k_atom<<<NNODES * 64 / 256, 256, 0, stream>>>(nf, atom_emb, x);
    k_rootinit<<<NNODES * 32 / 256, 256, 0, stream>>>(x, root, cbias, out);
    // 2. edge combo ids + dedup'd edge embeddings
    k_cid<<<(NEDGES + 255) / 256, 256, 0, stream>>>(ef, cid);
    k_etab<<<NCOMBO * 16 / 256, 256, 0, stream>>>(bond_emb, etab);
    // 3. edge MLP on 512 unique combos
    k_gemm_naive<<<NCOMBO * 1024 / 256, 256, 0, stream>>>(etab, gW1, nullptr, h1,
                                                          NCOMBO, 1024, 16, 1);
    k_gemm_tiled<64, 64, 16, 4, 4><<<dim3(4, 8, 16), 256, 0, stream>>>(
        h1, gW2, nullptr, nullptr, part, NCOMBO, 256, 1024, 64, 0);
    k_reduceK<<<131072 / 1024, 256, 0, stream>>>(part, nullptr, h2, 131072, 256, 16, 1);
    k_gemm_tiled<64, 64, 16, 4, 4><<<dim3(32, 8, 2), 256, 0, stream>>>(
        h2, gW3, nullptr, nullptr, part, NCOMBO, 2048, 256, 128, 0);
    k_reduceK<<<1048576 / 1024, 256, 0, stream>>>(part, nullptr, wtab, 1048576, 2048, 2, 0);
    // 4. per-edge message (plain store) + per-graph deterministic reduce
    k_msgp<<<NEDGES * 32 / 256, 256, 0, stream>>>(x, wtab, cid, src, msg);
    k_gred<<<NG, 256, 0, stream>>>(msg, dst, out);
    // 5. readout: f1 = relu(dense @ mW1 + mb1), dense == out viewed [1024,1280]
    k_gemm_tiled<64, 64, 16, 4, 4><<<dim3(4, 16, 8), 256, 0, stream>>>(
        out, mW1, nullptr, nullptr, part, NG, 256, 1280, 160, 0);
    k_reduceK<<<262144 / 1024, 256, 0, stream>>>(part, mb1, f1, 262144, 256, 8, 1);
    // f2 = relu(f1 @ mW2 + mb2): 1024x128, K=256, split 4x64
    k_gemm_tiled<64, 64, 16, 4, 4><<<dim3(2, 16, 4), 256, 0, stream>>>(
        f1, mW2, nullptr, nullptr, part, NG, 128, 256, 64, 0);
    k_reduceK<<<131072 / 1024, 256, 0, stream>>>(part, mb2, f2, 131072, 128, 4, 1);
    // 6. fused tail: f3, f4, final
    k_tail<<<NG / 4, 256, 0, stream>>>(f2, mW3, mb3, mW4, mb4, mW5, mb5, (float*)d_out);
}

// Round 8
// 242.032 us; speedup vs baseline: 1.1387x; 1.0569x over previous
//
#include <hip/hip_runtime.h>

#define NNODES 40960
#define NEDGES 81920
#define NG     1024
#define NCOMBO 512

// ---------- atom encoder: x[n,d] = sum_c atom_emb[c, nf[n,c], d] ----------
__global__ void k_atom(const int* __restrict__ nf, const float* __restrict__ emb,
                       float* __restrict__ x) {
    int gid = blockIdx.x * blockDim.x + threadIdx.x;   // NNODES*64
    int n = gid >> 6, d = gid & 63;
    const int* nfr = nf + n * 9;
    float acc = 0.f;
#pragma unroll
    for (int c = 0; c < 9; ++c) {
        int idx = nfr[c];
        acc += emb[((c << 7) + idx) * 64 + d];
    }
    x[gid] = acc;
}

// ---------- out_init[n,o] = bias[o] + sum_d x[n,d]*root[d,o] ----------
__global__ void k_rootinit(const float* __restrict__ x, const float* __restrict__ root,
                           const float* __restrict__ bias, float* __restrict__ out) {
    int gid = blockIdx.x * blockDim.x + threadIdx.x;   // NNODES*32
    int n = gid >> 5, o = gid & 31;
    const float* xr = x + n * 64;
    float acc = bias[o];
#pragma unroll
    for (int d = 0; d < 64; ++d) acc += xr[d] * root[d * 32 + o];
    out[gid] = acc;
}

// ---------- dedup: combo id per edge ----------
__global__ void k_cid(const int* __restrict__ ef, int* __restrict__ cid) {
    int e = blockIdx.x * blockDim.x + threadIdx.x;
    if (e < NEDGES)
        cid[e] = (ef[e * 3] << 6) | (ef[e * 3 + 1] << 3) | ef[e * 3 + 2];
}

// ---------- etab[c,j] = sum of 3 bond embeddings ----------
__global__ void k_etab(const float* __restrict__ bemb, float* __restrict__ etab) {
    int gid = blockIdx.x * blockDim.x + threadIdx.x;   // 512*16
    int c = gid >> 4, j = gid & 15;
    int f0 = c >> 6, f1 = (c >> 3) & 7, f2 = c & 7;
    etab[gid] = bemb[(0 * 8 + f0) * 16 + j] + bemb[(1 * 8 + f1) * 16 + j] +
                bemb[(2 * 8 + f2) * 16 + j];
}

// ---------- naive GEMM (small K only): C = relu?(A@B + bias) ----------
__global__ void k_gemm_naive(const float* __restrict__ A, const float* __restrict__ B,
                             const float* __restrict__ bias, float* __restrict__ C,
                             int M, int N, int K, int relu) {
    int gid = blockIdx.x * blockDim.x + threadIdx.x;
    if (gid >= M * N) return;
    int m = gid / N, n = gid - m * N;
    const float* a = A + m * K;
    float acc = bias ? bias[n] : 0.f;
    for (int k = 0; k < K; ++k) acc += a[k] * B[k * N + n];
    if (relu) acc = fmaxf(acc, 0.f);
    C[gid] = acc;
}

// ---------- tiled GEMM, 64x64 block tile, 4x4 micro tile, split-K over z ------
template <int BM, int BN, int BK, int TM, int TN>
__global__ __launch_bounds__(256)
void k_gemm_tiled(const float* __restrict__ A, const float* __restrict__ B,
                  const float* __restrict__ bias, float* __restrict__ C,
                  float* __restrict__ Cp, int M, int N, int K, int KS, int relu) {
    constexpr int TX = BN / TN;                 // 16
    constexpr int TY = BM / TM;                 // 16
    static_assert(TX * TY == 256, "block must be 256 threads");
    __shared__ float As[BK][BM + 4];            // transposed A tile
    __shared__ float Bs[BK][BN + 4];
    const int tx = threadIdx.x % TX, ty = threadIdx.x / TX;
    const int row0 = blockIdx.y * BM, col0 = blockIdx.x * BN;
    const int z = blockIdx.z;
    const int k_begin = z * KS, k_end = k_begin + KS;

    const int am = threadIdx.x >> 2;            // 0..63
    const int ak = (threadIdx.x & 3) << 2;      // 0,4,8,12
    const int bk = threadIdx.x >> 4;            // 0..15
    const int bn = (threadIdx.x & 15) << 2;     // 0..60

    float acc[TM][TN] = {};
    for (int k0 = k_begin; k0 < k_end; k0 += BK) {
        float4 av = *reinterpret_cast<const float4*>(&A[(row0 + am) * K + k0 + ak]);
        float4 bv = *reinterpret_cast<const float4*>(&B[(k0 + bk) * N + col0 + bn]);
        As[ak + 0][am] = av.x;
        As[ak + 1][am] = av.y;
        As[ak + 2][am] = av.z;
        As[ak + 3][am] = av.w;
        *reinterpret_cast<float4*>(&Bs[bk][bn]) = bv;
        __syncthreads();
#pragma unroll
        for (int k = 0; k < BK; ++k) {
            float a[TM], b[TN];
            *reinterpret_cast<float4*>(a) =
                *reinterpret_cast<const float4*>(&As[k][ty * TM]);
            *reinterpret_cast<float4*>(b) =
                *reinterpret_cast<const float4*>(&Bs[k][tx * TN]);
#pragma unroll
            for (int i = 0; i < TM; ++i)
#pragma unroll
                for (int j = 0; j < TN; ++j) acc[i][j] += a[i] * b[j];
        }
        __syncthreads();
    }

    const int MN = M * N;
    if (gridDim.z == 1) {
#pragma unroll
        for (int i = 0; i < TM; ++i) {
            int r = row0 + ty * TM + i;
            float4 v;
            v.x = acc[i][0]; v.y = acc[i][1]; v.z = acc[i][2]; v.w = acc[i][3];
            int c = col0 + tx * TN;
            if (bias) { v.x += bias[c]; v.y += bias[c+1]; v.z += bias[c+2]; v.w += bias[c+3]; }
            if (relu) { v.x = fmaxf(v.x,0.f); v.y = fmaxf(v.y,0.f);
                        v.z = fmaxf(v.z,0.f); v.w = fmaxf(v.w,0.f); }
            *reinterpret_cast<float4*>(&C[r * N + c]) = v;
        }
    } else {
        float* dstp = Cp + z * MN;
#pragma unroll
        for (int i = 0; i < TM; ++i) {
            int r = row0 + ty * TM + i;
            float4 v;
            v.x = acc[i][0]; v.y = acc[i][1]; v.z = acc[i][2]; v.w = acc[i][3];
            *reinterpret_cast<float4*>(&dstp[r * N + col0 + tx * TN]) = v;
        }
    }
}

// ---------- split-K reduce: C = relu?(sum_z Cp[z] + bias) ----------
__global__ void k_reduceK(const float* __restrict__ Cp, const float* __restrict__ bias,
                          float* __restrict__ C, int MN, int N, int nz, int relu) {
    int i4 = (blockIdx.x * 256 + threadIdx.x) * 4;
    if (i4 >= MN) return;
    float4 acc = *reinterpret_cast<const float4*>(&Cp[i4]);
    for (int z = 1; z < nz; ++z) {
        float4 t = *reinterpret_cast<const float4*>(&Cp[z * MN + i4]);
        acc.x += t.x; acc.y += t.y; acc.z += t.z; acc.w += t.w;
    }
    if (bias) {
        int c = i4 % N;
        acc.x += bias[c]; acc.y += bias[c + 1]; acc.z += bias[c + 2]; acc.w += bias[c + 3];
    }
    if (relu) {
        acc.x = fmaxf(acc.x, 0.f); acc.y = fmaxf(acc.y, 0.f);
        acc.z = fmaxf(acc.z, 0.f); acc.w = fmaxf(acc.w, 0.f);
    }
    *reinterpret_cast<float4*>(&C[i4]) = acc;
}

// ---------- NNConv message + scatter, 8 threads/edge, float4 ILP ----------
// thread = (edge, sub); sub owns output cols 4*sub..4*sub+3.
// Per thread: 16 x-float4 + 64 w-float4 independent loads, 256 FMAs, 4 atomics.
// 8 consecutive threads read one 128B W line per k -> fully coalesced.
__global__ void k_msg4(const float* __restrict__ x, const float* __restrict__ wtab,
                       const int* __restrict__ cid, const int* __restrict__ src,
                       const int* __restrict__ dst, float* __restrict__ out) {
    int gid = blockIdx.x * blockDim.x + threadIdx.x;   // NEDGES*8
    int e = gid >> 3, sub = gid & 7;
    int s = src[e], d = dst[e], c = cid[e];
    const float4* xv = reinterpret_cast<const float4*>(x + s * 64);
    const float*  w  = wtab + c * 2048 + sub * 4;      // w[k*32 + sub*4 + j]
    float4 acc = make_float4(0.f, 0.f, 0.f, 0.f);
#pragma unroll
    for (int k4 = 0; k4 < 16; ++k4) {
        float4 xq = xv[k4];
        float4 w0 = *reinterpret_cast<const float4*>(w + (4 * k4 + 0) * 32);
        float4 w1 = *reinterpret_cast<const float4*>(w + (4 * k4 + 1) * 32);
        float4 w2 = *reinterpret_cast<const float4*>(w + (4 * k4 + 2) * 32);
        float4 w3 = *reinterpret_cast<const float4*>(w + (4 * k4 + 3) * 32);
        acc.x += xq.x * w0.x; acc.y += xq.x * w0.y;
        acc.z += xq.x * w0.z; acc.w += xq.x * w0.w;
        acc.x += xq.y * w1.x; acc.y += xq.y * w1.y;
        acc.z += xq.y * w1.z; acc.w += xq.y * w1.w;
        acc.x += xq.z * w2.x; acc.y += xq.z * w2.y;
        acc.z += xq.z * w2.z; acc.w += xq.z * w2.w;
        acc.x += xq.w * w3.x; acc.y += xq.w * w3.y;
        acc.z += xq.w * w3.z; acc.w += xq.w * w3.w;
    }
    float* op = out + d * 32 + sub * 4;
    atomicAdd(op + 0, acc.x);
    atomicAdd(op + 1, acc.y);
    atomicAdd(op + 2, acc.z);
    atomicAdd(op + 3, acc.w);
}

// ---------- fused readout tail: f2[1024,128] -> f3 -> f4 -> out[1024] --------
__global__ __launch_bounds__(256) void k_tail(
    const float* __restrict__ f2,
    const float* __restrict__ mW3, const float* __restrict__ mb3,
    const float* __restrict__ mW4, const float* __restrict__ mb4,
    const float* __restrict__ mW5, const float* __restrict__ mb5,
    float* __restrict__ outv) {
    __shared__ float s2[4][128];
    __shared__ float s3[4][32];
    __shared__ float s4[4][8];
    const int w = threadIdx.x >> 6, lane = threadIdx.x & 63;
    const int g = blockIdx.x * 4 + w;
    s2[w][lane] = f2[g * 128 + lane];
    s2[w][64 + lane] = f2[g * 128 + 64 + lane];
    __syncthreads();
    if (lane < 32) {
        float acc = mb3[lane];
#pragma unroll 8
        for (int k = 0; k < 128; ++k) acc += s2[w][k] * mW3[k * 32 + lane];
        s3[w][lane] = fmaxf(acc, 0.f);
    }
    __syncthreads();
    if (lane < 8) {
        float acc = mb4[lane];
#pragma unroll
        for (int k = 0; k < 32; ++k) acc += s3[w][k] * mW4[k * 8 + lane];
        s4[w][lane] = fmaxf(acc, 0.f);
    }
    __syncthreads();
    if (lane == 0) {
        float acc = mb5[0];
#pragma unroll
        for (int k = 0; k < 8; ++k) acc += s4[w][k] * mW5[k];
        outv[g] = acc;
    }
}

extern "C" void kernel_launch(void* const* d_in, const int* in_sizes, int n_in,
                              void* d_out, int out_size, void* d_ws, size_t ws_size,
                              hipStream_t stream) {
    const int*   nf      = (const int*)d_in[0];
    const int*   ef      = (const int*)d_in[1];
    const int*   eidx    = (const int*)d_in[2];
    const float* atom_emb= (const float*)d_in[4];
    const float* bond_emb= (const float*)d_in[5];
    const float* gW1     = (const float*)d_in[6];
    const float* gW2     = (const float*)d_in[7];
    const float* gW3     = (const float*)d_in[8];
    const float* root    = (const float*)d_in[9];
    const float* cbias   = (const float*)d_in[10];
    const float* mW1     = (const float*)d_in[11];
    const float* mb1     = (const float*)d_in[12];
    const float* mW2     = (const float*)d_in[13];
    const float* mb2     = (const float*)d_in[14];
    const float* mW3     = (const float*)d_in[15];
    const float* mb3     = (const float*)d_in[16];
    const float* mW4     = (const float*)d_in[17];
    const float* mb4     = (const float*)d_in[18];
    const float* mW5     = (const float*)d_in[19];
    const float* mb5     = (const float*)d_in[20];

    const int* src = eidx;
    const int* dst = eidx + NEDGES;

    float* ws = (float*)d_ws;
    float* x    = ws;                       // 40960*64   = 2621440
    float* out  = x + 2621440;              // 40960*32   = 1310720
    float* etab = out + 1310720;            // 512*16     = 8192
    float* h1   = etab + 8192;              // 512*1024   = 524288
    float* h2   = h1 + 524288;              // 512*256    = 131072
    float* wtab = h2 + 131072;              // 512*2048   = 1048576
    float* f1   = wtab + 1048576;           // 1024*256   = 262144
    float* f2   = f1 + 262144;              // 1024*128   = 131072
    float* part = f2 + 131072;              // 2097152 (8 MB split-K partials)
    int*   cid  = (int*)(part + 2097152);   // 81920 ints

    // 1. atom encoder + root transform (agg initializer)
    k_atom<<<NNODES * 64 / 256, 256, 0, stream>>>(nf, atom_emb, x);
    k_rootinit<<<NNODES * 32 / 256, 256, 0, stream>>>(x, root, cbias, out);
    // 2. edge combo ids + dedup'd edge embeddings
    k_cid<<<(NEDGES + 255) / 256, 256, 0, stream>>>(ef, cid);
    k_etab<<<NCOMBO * 16 / 256, 256, 0, stream>>>(bond_emb, etab);
    // 3. edge MLP on 512 unique combos
    k_gemm_naive<<<NCOMBO * 1024 / 256, 256, 0, stream>>>(etab, gW1, nullptr, h1,
                                                          NCOMBO, 1024, 16, 1);
    k_gemm_tiled<64, 64, 16, 4, 4><<<dim3(4, 8, 16), 256, 0, stream>>>(
        h1, gW2, nullptr, nullptr, part, NCOMBO, 256, 1024, 64, 0);
    k_reduceK<<<131072 / 1024, 256, 0, stream>>>(part, nullptr, h2, 131072, 256, 16, 1);
    k_gemm_tiled<64, 64, 16, 4, 4><<<dim3(32, 8, 2), 256, 0, stream>>>(
        h2, gW3, nullptr, nullptr, part, NCOMBO, 2048, 256, 128, 0);
    k_reduceK<<<1048576 / 1024, 256, 0, stream>>>(part, nullptr, wtab, 1048576, 2048, 2, 0);
    // 4. per-edge message + scatter-add (8 threads/edge, float4 ILP)
    k_msg4<<<NEDGES * 8 / 256, 256, 0, stream>>>(x, wtab, cid, src, dst, out);
    // 5. readout: f1 = relu(dense @ mW1 + mb1), dense == out viewed [1024,1280]
    k_gemm_tiled<64, 64, 16, 4, 4><<<dim3(4, 16, 8), 256, 0, stream>>>(
        out, mW1, nullptr, nullptr, part, NG, 256, 1280, 160, 0);
    k_reduceK<<<262144 / 1024, 256, 0, stream>>>(part, mb1, f1, 262144, 256, 8, 1);
    // f2 = relu(f1 @ mW2 + mb2): 1024x128, K=256, split 4x64
    k_gemm_tiled<64, 64, 16, 4, 4><<<dim3(2, 16, 4), 256, 0, stream>>>(
        f1, mW2, nullptr, nullptr, part, NG, 128, 256, 64, 0);
    k_reduceK<<<131072 / 1024, 256, 0, stream>>>(part, mb2, f2, 131072, 128, 4, 1);
    // 6. fused tail: f3, f4, final
    k_tail<<<NG / 4, 256, 0, stream>>>(f2, mW3, mb3, mW4, mb4, mW5, mb5, (float*)d_out);
}

// Round 9
// 233.824 us; speedup vs baseline: 1.1787x; 1.0351x over previous
//
#include <hip/hip_runtime.h>

#define NNODES 40960
#define NEDGES 81920
#define NG     1024
#define NCOMBO 512

// ---------- fused node encoder: x[n,:], then out_init[n,:] = bias + x@root ---
// block = 256 threads = 4 nodes x 64 dims (proven in rounds 2-4)
__global__ __launch_bounds__(256) void k_node(
    const int* __restrict__ nf, const float* __restrict__ emb,
    const float* __restrict__ root, const float* __restrict__ bias,
    float* __restrict__ x, float* __restrict__ out) {
    __shared__ float sx[4][64];
    const int t = threadIdx.x;
    const int ln = t >> 6;                 // local node 0..3
    const int d  = t & 63;
    const int n  = blockIdx.x * 4 + ln;
    const int* nfr = nf + n * 9;
    float acc = 0.f;
#pragma unroll
    for (int c = 0; c < 9; ++c) {
        int idx = nfr[c];
        acc += emb[((c << 7) + idx) * 64 + d];
    }
    x[n * 64 + d] = acc;
    sx[ln][d] = acc;
    __syncthreads();
    if (d < 32) {
        float o = bias[d];
#pragma unroll
        for (int k = 0; k < 64; ++k) o += sx[ln][k] * root[k * 32 + d];
        out[n * 32 + d] = o;
    }
}

// ---------- h1[c,:] = relu(etab[c] @ gW1), etab computed in-LDS ----------
// 2048 blocks: c = b>>2, 256 cols per block (proven pattern in round 3 prep)
__global__ __launch_bounds__(256) void k_h1(
    const float* __restrict__ bemb, const float* __restrict__ gW1,
    float* __restrict__ h1) {
    __shared__ float se[16];
    const int b = blockIdx.x, t = threadIdx.x;
    const int c = b >> 2;
    const int n = ((b & 3) << 8) + t;
    if (t < 16) {
        int f0 = c >> 6, f1 = (c >> 3) & 7, f2 = c & 7;
        se[t] = bemb[f0 * 16 + t] + bemb[(8 + f1) * 16 + t] +
                bemb[(16 + f2) * 16 + t];
    }
    __syncthreads();
    float acc = 0.f;
#pragma unroll
    for (int k = 0; k < 16; ++k) acc += se[k] * gW1[k * 1024 + n];
    h1[c * 1024 + n] = fmaxf(acc, 0.f);
}

// ---------- tiled GEMM, 64x64 block tile, 4x4 micro tile, split-K over z ------
template <int BM, int BN, int BK, int TM, int TN>
__global__ __launch_bounds__(256)
void k_gemm_tiled(const float* __restrict__ A, const float* __restrict__ B,
                  const float* __restrict__ bias, float* __restrict__ C,
                  float* __restrict__ Cp, int M, int N, int K, int KS, int relu) {
    constexpr int TX = BN / TN;                 // 16
    constexpr int TY = BM / TM;                 // 16
    static_assert(TX * TY == 256, "block must be 256 threads");
    __shared__ float As[BK][BM + 4];            // transposed A tile
    __shared__ float Bs[BK][BN + 4];
    const int tx = threadIdx.x % TX, ty = threadIdx.x / TX;
    const int row0 = blockIdx.y * BM, col0 = blockIdx.x * BN;
    const int z = blockIdx.z;
    const int k_begin = z * KS, k_end = k_begin + KS;

    const int am = threadIdx.x >> 2;            // 0..63
    const int ak = (threadIdx.x & 3) << 2;      // 0,4,8,12
    const int bk = threadIdx.x >> 4;            // 0..15
    const int bn = (threadIdx.x & 15) << 2;     // 0..60

    float acc[TM][TN] = {};
    for (int k0 = k_begin; k0 < k_end; k0 += BK) {
        float4 av = *reinterpret_cast<const float4*>(&A[(row0 + am) * K + k0 + ak]);
        float4 bv = *reinterpret_cast<const float4*>(&B[(k0 + bk) * N + col0 + bn]);
        As[ak + 0][am] = av.x;
        As[ak + 1][am] = av.y;
        As[ak + 2][am] = av.z;
        As[ak + 3][am] = av.w;
        *reinterpret_cast<float4*>(&Bs[bk][bn]) = bv;
        __syncthreads();
#pragma unroll
        for (int k = 0; k < BK; ++k) {
            float a[TM], b[TN];
            *reinterpret_cast<float4*>(a) =
                *reinterpret_cast<const float4*>(&As[k][ty * TM]);
            *reinterpret_cast<float4*>(b) =
                *reinterpret_cast<const float4*>(&Bs[k][tx * TN]);
#pragma unroll
            for (int i = 0; i < TM; ++i)
#pragma unroll
                for (int j = 0; j < TN; ++j) acc[i][j] += a[i] * b[j];
        }
        __syncthreads();
    }

    const int MN = M * N;
    if (gridDim.z == 1) {
#pragma unroll
        for (int i = 0; i < TM; ++i) {
            int r = row0 + ty * TM + i;
            float4 v;
            v.x = acc[i][0]; v.y = acc[i][1]; v.z = acc[i][2]; v.w = acc[i][3];
            int c = col0 + tx * TN;
            if (bias) { v.x += bias[c]; v.y += bias[c+1]; v.z += bias[c+2]; v.w += bias[c+3]; }
            if (relu) { v.x = fmaxf(v.x,0.f); v.y = fmaxf(v.y,0.f);
                        v.z = fmaxf(v.z,0.f); v.w = fmaxf(v.w,0.f); }
            *reinterpret_cast<float4*>(&C[r * N + c]) = v;
        }
    } else {
        float* dstp = Cp + z * MN;
#pragma unroll
        for (int i = 0; i < TM; ++i) {
            int r = row0 + ty * TM + i;
            float4 v;
            v.x = acc[i][0]; v.y = acc[i][1]; v.z = acc[i][2]; v.w = acc[i][3];
            *reinterpret_cast<float4*>(&dstp[r * N + col0 + tx * TN]) = v;
        }
    }
}

// ---------- split-K reduce: C = relu?(sum_z Cp[z] + bias) ----------
__global__ void k_reduceK(const float* __restrict__ Cp, const float* __restrict__ bias,
                          float* __restrict__ C, int MN, int N, int nz, int relu) {
    int i4 = (blockIdx.x * 256 + threadIdx.x) * 4;
    if (i4 >= MN) return;
    float4 acc = *reinterpret_cast<const float4*>(&Cp[i4]);
    for (int z = 1; z < nz; ++z) {
        float4 t = *reinterpret_cast<const float4*>(&Cp[z * MN + i4]);
        acc.x += t.x; acc.y += t.y; acc.z += t.z; acc.w += t.w;
    }
    if (bias) {
        int c = i4 % N;
        acc.x += bias[c]; acc.y += bias[c + 1]; acc.z += bias[c + 2]; acc.w += bias[c + 3];
    }
    if (relu) {
        acc.x = fmaxf(acc.x, 0.f); acc.y = fmaxf(acc.y, 0.f);
        acc.z = fmaxf(acc.z, 0.f); acc.w = fmaxf(acc.w, 0.f);
    }
    *reinterpret_cast<float4*>(&C[i4]) = acc;
}

// ---------- NNConv message + scatter (round-0 body, cid computed inline) -----
__global__ void k_msg(const float* __restrict__ x, const float* __restrict__ wtab,
                      const int* __restrict__ ef, const int* __restrict__ src,
                      const int* __restrict__ dst, float* __restrict__ out) {
    int gid = blockIdx.x * blockDim.x + threadIdx.x;   // NEDGES*32
    int e = gid >> 5, o = gid & 31;
    int s = src[e], d = dst[e];
    int c = (ef[e * 3] << 6) | (ef[e * 3 + 1] << 3) | ef[e * 3 + 2];
    const float* xr = x + s * 64;
    const float* w = wtab + c * 2048 + o;
    float acc = 0.f;
#pragma unroll
    for (int k = 0; k < 64; ++k) acc += xr[k] * w[k * 32];
    atomicAdd(&out[d * 32 + o], acc);
}

// ---------- fused readout tail: f1 -> f2 -> f3 -> f4 -> out, 4 graphs/block --
__global__ __launch_bounds__(256) void k_tail2(
    const float* __restrict__ f1,
    const float* __restrict__ mW2, const float* __restrict__ mb2,
    const float* __restrict__ mW3, const float* __restrict__ mb3,
    const float* __restrict__ mW4, const float* __restrict__ mb4,
    const float* __restrict__ mW5, const float* __restrict__ mb5,
    float* __restrict__ outv) {
    __shared__ float s1[4][256];
    __shared__ float s2[4][128];
    __shared__ float s3[4][32];
    __shared__ float s4[4][8];
    const int t  = threadIdx.x;
    const int g0 = blockIdx.x * 4;
    // stage 4 f1 rows (1024 floats), coalesced
#pragma unroll
    for (int i = 0; i < 4; ++i) {
        int idx = t + i * 256;
        s1[idx >> 8][idx & 255] = f1[g0 * 256 + idx];
    }
    __syncthreads();
    // f2 = relu(f1 @ mW2 + mb2): 4 graphs x 128 cols, 2 outputs/thread
#pragma unroll
    for (int i = 0; i < 2; ++i) {
        int idx = t + i * 256;
        int g = idx >> 7, cc = idx & 127;
        float acc = mb2[cc];
#pragma unroll 8
        for (int k = 0; k < 256; ++k) acc += s1[g][k] * mW2[k * 128 + cc];
        s2[g][cc] = fmaxf(acc, 0.f);
    }
    __syncthreads();
    // f3/f4/f5: round-0 tail body (4 x 64-lane groups, one graph each)
    const int w = t >> 6, lane = t & 63;
    if (lane < 32) {
        float acc = mb3[lane];
#pragma unroll 8
        for (int k = 0; k < 128; ++k) acc += s2[w][k] * mW3[k * 32 + lane];
        s3[w][lane] = fmaxf(acc, 0.f);
    }
    __syncthreads();
    if (lane < 8) {
        float acc = mb4[lane];
#pragma unroll
        for (int k = 0; k < 32; ++k) acc += s3[w][k] * mW4[k * 8 + lane];
        s4[w][lane] = fmaxf(acc, 0.f);
    }
    __syncthreads();
    if (lane == 0) {
        float acc = mb5[0];
#pragma unroll
        for (int k = 0; k < 8; ++k) acc += s4[w][k] * mW5[k];
        outv[g0 + w] = acc;
    }
}

extern "C" void kernel_launch(void* const* d_in, const int* in_sizes, int n_in,
                              void* d_out, int out_size, void* d_ws, size_t ws_size,
                              hipStream_t stream) {
    const int*   nf      = (const int*)d_in[0];
    const int*   ef      = (const int*)d_in[1];
    const int*   eidx    = (const int*)d_in[2];
    const float* atom_emb= (const float*)d_in[4];
    const float* bond_emb= (const float*)d_in[5];
    const float* gW1     = (const float*)d_in[6];
    const float* gW2     = (const float*)d_in[7];
    const float* gW3     = (const float*)d_in[8];
    const float* root    = (const float*)d_in[9];
    const float* cbias   = (const float*)d_in[10];
    const float* mW1     = (const float*)d_in[11];
    const float* mb1     = (const float*)d_in[12];
    const float* mW2     = (const float*)d_in[13];
    const float* mb2     = (const float*)d_in[14];
    const float* mW3     = (const float*)d_in[15];
    const float* mb3     = (const float*)d_in[16];
    const float* mW4     = (const float*)d_in[17];
    const float* mb4     = (const float*)d_in[18];
    const float* mW5     = (const float*)d_in[19];
    const float* mb5     = (const float*)d_in[20];

    const int* src = eidx;
    const int* dst = eidx + NEDGES;

    float* ws = (float*)d_ws;
    float* x    = ws;                       // 40960*64   = 2621440
    float* out  = x + 2621440;              // 40960*32   = 1310720
    float* h1   = out + 1310720;            // 512*1024   = 524288
    float* h2   = h1 + 524288;              // 512*256    = 131072
    float* wtab = h2 + 131072;              // 512*2048   = 1048576
    float* f1   = wtab + 1048576;           // 1024*256   = 262144
    float* part = f1 + 262144;              // 2097152 (8 MB split-K partials)

    // 1. fused atom encoder + root transform
    k_node<<<NNODES / 4, 256, 0, stream>>>(nf, atom_emb, root, cbias, x, out);
    // 2. h1 = relu(etab @ gW1), etab computed in-LDS per block
    k_h1<<<NCOMBO * 4, 256, 0, stream>>>(bond_emb, gW1, h1);
    // 3. h2 = relu(h1 @ gW2): 512x256, K=1024, split 16x64
    k_gemm_tiled<64, 64, 16, 4, 4><<<dim3(4, 8, 16), 256, 0, stream>>>(
        h1, gW2, nullptr, nullptr, part, NCOMBO, 256, 1024, 64, 0);
    k_reduceK<<<131072 / 1024, 256, 0, stream>>>(part, nullptr, h2, 131072, 256, 16, 1);
    // 4. wtab = h2 @ gW3: 512x2048, K=256, split 2x128
    k_gemm_tiled<64, 64, 16, 4, 4><<<dim3(32, 8, 2), 256, 0, stream>>>(
        h2, gW3, nullptr, nullptr, part, NCOMBO, 2048, 256, 128, 0);
    k_reduceK<<<1048576 / 1024, 256, 0, stream>>>(part, nullptr, wtab, 1048576, 2048, 2, 0);
    // 5. per-edge message + scatter-add (round-0 body, cid inline)
    k_msg<<<NEDGES * 32 / 256, 256, 0, stream>>>(x, wtab, ef, src, dst, out);
    // 6. f1 = relu(dense @ mW1 + mb1): 1024x256, K=1280, split 8x160
    k_gemm_tiled<64, 64, 16, 4, 4><<<dim3(4, 16, 8), 256, 0, stream>>>(
        out, mW1, nullptr, nullptr, part, NG, 256, 1280, 160, 0);
    k_reduceK<<<262144 / 1024, 256, 0, stream>>>(part, mb1, f1, 262144, 256, 8, 1);
    // 7. fused tail: f2, f3, f4, final
    k_tail2<<<NG / 4, 256, 0, stream>>>(f1, mW2, mb2, mW3, mb3, mW4, mb4,
                                        mW5, mb5, (float*)d_out);
}